// Round 1
// baseline (1820.872 us; speedup 1.0000x reference)
//
#include <hip/hip_runtime.h>
#include <math.h>

#define N_ROWS 262144
#define K_CODES 1024
#define D_DIM 64

// ---------------------------------------------------------------------------
// Kernel 1: c_sq[k] = sum_d cb[k][d]^2   (K=1024, trivial)
// ---------------------------------------------------------------------------
__global__ __launch_bounds__(256) void csq_kernel(const float* __restrict__ cb,
                                                  float* __restrict__ c_sq) {
    int k = blockIdx.x * 256 + threadIdx.x;
    if (k >= K_CODES) return;
    const float4* row = (const float4*)(cb + (size_t)k * D_DIM);
    float s = 0.0f;
#pragma unroll
    for (int j = 0; j < D_DIM / 4; ++j) {
        float4 v = row[j];
        s = fmaf(v.x, v.x, s);
        s = fmaf(v.y, v.y, s);
        s = fmaf(v.z, v.z, s);
        s = fmaf(v.w, v.w, s);
    }
    c_sq[k] = s;
}

// ---------------------------------------------------------------------------
// Kernel 2: per-row argmin over K codes + residual/embedding writeout.
// One thread = one row. Row cached in 64 VGPRs. Codebook accessed via
// wave-uniform index -> scalar loads (s_load), zero VMEM pressure in the
// hot loop. 2 codes per iteration x 4 partial accumulators = 8 independent
// fmaf chains for ILP.
// ---------------------------------------------------------------------------
__global__ __launch_bounds__(256) void vq_kernel(const float* __restrict__ x_all,
                                                 const float* __restrict__ cb,
                                                 const float* __restrict__ c_sq,
                                                 float* __restrict__ out_idx,
                                                 float* __restrict__ out_res,
                                                 float* __restrict__ out_emb) {
    const int r = blockIdx.x * 256 + threadIdx.x;   // grid sized exactly

    // ---- load row into registers (16x float4, contiguous 256B per thread;
    //      the wave covers a contiguous 16KB span -> L1-friendly) ----
    float x[D_DIM];
    {
        const float4* xr = (const float4*)(x_all + (size_t)r * D_DIM);
#pragma unroll
        for (int j = 0; j < D_DIM / 4; ++j) {
            float4 v = xr[j];
            x[4 * j + 0] = v.x;
            x[4 * j + 1] = v.y;
            x[4 * j + 2] = v.z;
            x[4 * j + 3] = v.w;
        }
    }

    // x_sq is a per-row constant: its rounding error is shared by all k and
    // cannot flip the argmin.
    float x_sq = 0.0f;
#pragma unroll
    for (int d = 0; d < D_DIM; ++d) x_sq = fmaf(x[d], x[d], x_sq);

    float best = INFINITY;
    int bidx = 0;

#pragma unroll 2
    for (int k = 0; k < K_CODES; k += 2) {
        const float* c0 = cb + (size_t)k * D_DIM;   // wave-uniform -> s_load
        const float* c1 = c0 + D_DIM;

        float a00 = 0.f, a01 = 0.f, a02 = 0.f, a03 = 0.f;
        float a10 = 0.f, a11 = 0.f, a12 = 0.f, a13 = 0.f;
#pragma unroll
        for (int d = 0; d < 16; ++d) {
            a00 = fmaf(x[d],      c0[d],      a00);
            a10 = fmaf(x[d],      c1[d],      a10);
            a01 = fmaf(x[d + 16], c0[d + 16], a01);
            a11 = fmaf(x[d + 16], c1[d + 16], a11);
            a02 = fmaf(x[d + 32], c0[d + 32], a02);
            a12 = fmaf(x[d + 32], c1[d + 32], a12);
            a03 = fmaf(x[d + 48], c0[d + 48], a03);
            a13 = fmaf(x[d + 48], c1[d + 48], a13);
        }
        float dot0 = (a00 + a01) + (a02 + a03);
        float dot1 = (a10 + a11) + (a12 + a13);

        // match reference expansion order: (x_sq - 2*xc) + c_sq
        float d0 = (x_sq - 2.0f * dot0) + c_sq[k];
        float d1 = (x_sq - 2.0f * dot1) + c_sq[k + 1];

        // strict '<' + ascending k == np.argmin first-occurrence tie-break
        if (d0 < best) { best = d0; bidx = k; }
        if (d1 < best) { best = d1; bidx = k + 1; }
    }

    // ---- epilogue: re-load winning code (L2-hot, 256KB codebook), write
    //      index-as-float, residual, embedding ----
    const float4* cbest = (const float4*)(cb + (size_t)bidx * D_DIM);
    float4* res = (float4*)(out_res + (size_t)r * D_DIM);
    float4* emb = (float4*)(out_emb + (size_t)r * D_DIM);
#pragma unroll
    for (int j = 0; j < D_DIM / 4; ++j) {
        float4 c = cbest[j];
        float4 v;
        v.x = x[4 * j + 0] - c.x;
        v.y = x[4 * j + 1] - c.y;
        v.z = x[4 * j + 2] - c.z;
        v.w = x[4 * j + 3] - c.w;
        res[j] = v;
        emb[j] = c;
    }
    out_idx[r] = (float)bidx;
}

extern "C" void kernel_launch(void* const* d_in, const int* in_sizes, int n_in,
                              void* d_out, int out_size, void* d_ws, size_t ws_size,
                              hipStream_t stream) {
    const float* x  = (const float*)d_in[0];   // [N, D] fp32
    const float* cb = (const float*)d_in[1];   // [K, D] fp32

    float* c_sq = (float*)d_ws;                // K floats of scratch

    float* out    = (float*)d_out;
    float* o_idx  = out;                                   // [N]    index as float
    float* o_res  = out + (size_t)N_ROWS;                  // [N, D] next_residual
    float* o_emb  = o_res + (size_t)N_ROWS * D_DIM;        // [N, D] embedding

    csq_kernel<<<(K_CODES + 255) / 256, 256, 0, stream>>>(cb, c_sq);
    vq_kernel<<<N_ROWS / 256, 256, 0, stream>>>(x, cb, c_sq, o_idx, o_res, o_emb);
}

// Round 2
// 970.552 us; speedup vs baseline: 1.8761x; 1.8761x over previous
//
#include <hip/hip_runtime.h>
#include <math.h>

#define N_ROWS 262144
#define K_CODES 1024
#define D_DIM 64
#define WL_CAP 65536

typedef __attribute__((ext_vector_type(8))) short short8;
typedef __attribute__((ext_vector_type(4))) float f32x4;
typedef unsigned short ushortT;
typedef unsigned int uintT;

// bf16 round-to-nearest-even of a finite fp32, returned as raw bf16 bits.
__device__ inline uintT bf16_rne_bits(float v) {
    uintT u = __float_as_uint(v);
    return (u + 0x7FFFu + ((u >> 16) & 1u)) >> 16;
}

// ---------------------------------------------------------------------------
// Prep: c_sq (EXACT same accumulation order as the round-1 kernel that
// matched np with absmax 0.0), codebook bf16 hi/lo split, counter zero.
// ---------------------------------------------------------------------------
__global__ __launch_bounds__(256) void prep_kernel(const float* __restrict__ cb,
                                                   ushortT* __restrict__ cbh,
                                                   ushortT* __restrict__ cbl,
                                                   float* __restrict__ c_sq,
                                                   int* __restrict__ cnt) {
    if (blockIdx.x == 0 && threadIdx.x == 0) *cnt = 0;
    int k = blockIdx.x * 256 + threadIdx.x;
    if (k >= K_CODES) return;
    const float4* row = (const float4*)(cb + (size_t)k * D_DIM);
    float s = 0.0f;
#pragma unroll
    for (int j = 0; j < D_DIM / 4; ++j) {
        float4 v = row[j];
        s = fmaf(v.x, v.x, s);
        s = fmaf(v.y, v.y, s);
        s = fmaf(v.z, v.z, s);
        s = fmaf(v.w, v.w, s);
        float e[4] = {v.x, v.y, v.z, v.w};
#pragma unroll
        for (int q = 0; q < 4; ++q) {
            int d = 4 * j + q;
            uintT hb = bf16_rne_bits(e[q]);
            float hif = __uint_as_float(hb << 16);
            uintT lb = bf16_rne_bits(e[q] - hif);
            cbh[(size_t)k * D_DIM + d] = (ushortT)hb;
            cbl[(size_t)k * D_DIM + d] = (ushortT)lb;
        }
    }
    c_sq[k] = s;
}

// ---------------------------------------------------------------------------
// Coarse: 3-pass split-bf16 MFMA distances, per-row min1/min2/argmin,
// hard-bound gap test, direct output write; uncertain rows -> worklist.
// Block = 256 thr = 4 waves; wave handles 32 rows (2 rowsets of 16) x all K.
// ---------------------------------------------------------------------------
__global__ __launch_bounds__(256, 3) void coarse_kernel(
        const float* __restrict__ x_all, const float* __restrict__ cb,
        const ushortT* __restrict__ cbh, const ushortT* __restrict__ cbl,
        const float* __restrict__ c_sq_g,
        float* __restrict__ out_idx, float* __restrict__ out_res,
        float* __restrict__ out_emb, int* __restrict__ cnt,
        int* __restrict__ wl) {
    __shared__ uint4 stage4[2048];          // 32 KB: one round = 8 tiles of 16 codes, hi+lo
    __shared__ float csq_s[128];
    __shared__ float xsq_s[128];
    __shared__ int   idx_s[128];
    ushortT* stage = (ushortT*)stage4;

    const int t  = threadIdx.x;
    const int w  = t >> 6;          // wave 0..3
    const int L  = t & 63;          // lane
    const int q  = L >> 4;          // quad 0..3
    const int n  = L & 15;          // class / col
    const int rowbase = blockIdx.x * 128 + w * 32;

    // ---- load + convert A fragments (x rows), compute x_sq ----
    short8 ah[2][2], al[2][2];
#pragma unroll
    for (int s = 0; s < 2; ++s) {
        float part = 0.0f;
#pragma unroll
        for (int kt = 0; kt < 2; ++kt) {
            const float4* p = (const float4*)(x_all +
                (size_t)(rowbase + s * 16 + n) * D_DIM + kt * 32 + q * 8);
            float4 v0 = p[0], v1 = p[1];
            float e[8] = {v0.x, v0.y, v0.z, v0.w, v1.x, v1.y, v1.z, v1.w};
#pragma unroll
            for (int j = 0; j < 8; ++j) {
                part = fmaf(e[j], e[j], part);
                uintT hb = bf16_rne_bits(e[j]);
                float hif = __uint_as_float(hb << 16);
                uintT lb = bf16_rne_bits(e[j] - hif);
                ah[s][kt][j] = (short)hb;
                al[s][kt][j] = (short)lb;
            }
        }
        // reduce over quads (lanes n, n+16, n+32, n+48)
        part += __shfl_xor(part, 16);
        part += __shfl_xor(part, 32);
        if (q == 0) xsq_s[w * 32 + s * 16 + n] = part;
    }

    // ---- tracking state: per (rowset s, reg j) = per (row, class) ----
    float m1[2][4], m2[2][4];
    int   ix[2][4];
#pragma unroll
    for (int s = 0; s < 2; ++s)
#pragma unroll
        for (int j = 0; j < 4; ++j) { m1[s][j] = 3.4e38f; m2[s][j] = 3.4e38f; ix[s][j] = 0; }

    // ---- prologue: prefetch round 0 staging into registers ----
    uint4 pre[8];
    float cpre = 0.0f;
#pragma unroll
    for (int it = 0; it < 8; ++it) {
        int chunk = it * 256 + t;
        int tile = chunk >> 8, c = chunk & 255;
        int hilo = (c >> 7) & 1, cc = c & 127;
        int kt = cc >> 6, LL = cc & 63;
        const ushortT* src = hilo ? cbl : cbh;
        size_t elem = (size_t)(tile * 16 + (LL & 15)) * D_DIM + kt * 32 + (LL >> 4) * 8;
        pre[it] = *(const uint4*)(src + elem);
    }
    if (t < 128) cpre = c_sq_g[t];

    for (int r = 0; r < 8; ++r) {
        __syncthreads();                       // previous round's compute done
#pragma unroll
        for (int it = 0; it < 8; ++it)
            *(uint4*)(stage + (it * 256 + t) * 8) = pre[it];
        if (t < 128) csq_s[t] = cpre;
        __syncthreads();                       // staging visible

        if (r < 7) {                           // prefetch next round (overlaps compute)
            int rn = r + 1;
#pragma unroll
            for (int it = 0; it < 8; ++it) {
                int chunk = it * 256 + t;
                int tile = chunk >> 8, c = chunk & 255;
                int hilo = (c >> 7) & 1, cc = c & 127;
                int kt = cc >> 6, LL = cc & 63;
                const ushortT* src = hilo ? cbl : cbh;
                size_t elem = (size_t)(rn * 128 + tile * 16 + (LL & 15)) * D_DIM +
                              kt * 32 + (LL >> 4) * 8;
                pre[it] = *(const uint4*)(src + elem);
            }
            if (t < 128) cpre = c_sq_g[rn * 128 + t];
        }

        // ---- compute 8 tiles from LDS ----
#pragma unroll
        for (int tl = 0; tl < 8; ++tl) {
            const int tb = tl * 2048;          // ushort offset of tile
            short8 bh0 = *(const short8*)(stage + tb +        0 * 512 + L * 8);
            short8 bh1 = *(const short8*)(stage + tb +        1 * 512 + L * 8);
            short8 bl0 = *(const short8*)(stage + tb + 1024 + 0 * 512 + L * 8);
            short8 bl1 = *(const short8*)(stage + tb + 1024 + 1 * 512 + L * 8);

            f32x4 acc0 = {0.f, 0.f, 0.f, 0.f};
            f32x4 acc1 = {0.f, 0.f, 0.f, 0.f};
            acc0 = __builtin_amdgcn_mfma_f32_16x16x32_bf16(ah[0][0], bh0, acc0, 0, 0, 0);
            acc1 = __builtin_amdgcn_mfma_f32_16x16x32_bf16(ah[1][0], bh0, acc1, 0, 0, 0);
            acc0 = __builtin_amdgcn_mfma_f32_16x16x32_bf16(ah[0][1], bh1, acc0, 0, 0, 0);
            acc1 = __builtin_amdgcn_mfma_f32_16x16x32_bf16(ah[1][1], bh1, acc1, 0, 0, 0);
            acc0 = __builtin_amdgcn_mfma_f32_16x16x32_bf16(ah[0][0], bl0, acc0, 0, 0, 0);
            acc1 = __builtin_amdgcn_mfma_f32_16x16x32_bf16(ah[1][0], bl0, acc1, 0, 0, 0);
            acc0 = __builtin_amdgcn_mfma_f32_16x16x32_bf16(ah[0][1], bl1, acc0, 0, 0, 0);
            acc1 = __builtin_amdgcn_mfma_f32_16x16x32_bf16(ah[1][1], bl1, acc1, 0, 0, 0);
            acc0 = __builtin_amdgcn_mfma_f32_16x16x32_bf16(al[0][0], bh0, acc0, 0, 0, 0);
            acc1 = __builtin_amdgcn_mfma_f32_16x16x32_bf16(al[1][0], bh0, acc1, 0, 0, 0);
            acc0 = __builtin_amdgcn_mfma_f32_16x16x32_bf16(al[0][1], bh1, acc0, 0, 0, 0);
            acc1 = __builtin_amdgcn_mfma_f32_16x16x32_bf16(al[1][1], bh1, acc1, 0, 0, 0);

            float cv = csq_s[tl * 16 + n];
            int kc = r * 128 + tl * 16 + n;
#pragma unroll
            for (int j = 0; j < 4; ++j) {
                float d0 = fmaf(-2.0f, acc0[j], cv);
                bool lt0 = d0 < m1[0][j];
                m2[0][j] = lt0 ? m1[0][j] : fminf(m2[0][j], d0);
                m1[0][j] = lt0 ? d0 : m1[0][j];
                ix[0][j] = lt0 ? kc : ix[0][j];
                float d1 = fmaf(-2.0f, acc1[j], cv);
                bool lt1 = d1 < m1[1][j];
                m2[1][j] = lt1 ? m1[1][j] : fminf(m2[1][j], d1);
                m1[1][j] = lt1 ? d1 : m1[1][j];
                ix[1][j] = lt1 ? kc : ix[1][j];
            }
        }
    }

    // ---- butterfly reduce across the 16 classes (lane bits 0..3) ----
#pragma unroll
    for (int s = 0; s < 2; ++s)
#pragma unroll
        for (int j = 0; j < 4; ++j) {
            float a1 = m1[s][j], a2 = m2[s][j];
            int ai = ix[s][j];
#pragma unroll
            for (int msk = 1; msk < 16; msk <<= 1) {
                float o1 = __shfl_xor(a1, msk);
                float o2 = __shfl_xor(a2, msk);
                int oi = __shfl_xor(ai, msk);
                float nm2 = fminf(fmaxf(a1, o1), fminf(a2, o2));
                bool take = (o1 < a1) || (o1 == a1 && oi < ai);
                a1 = take ? o1 : a1;
                ai = take ? oi : ai;
                a2 = nm2;
            }
            m1[s][j] = a1; m2[s][j] = a2; ix[s][j] = ai;
        }

    // ---- gap test + record per-row result (class-0 lanes) ----
    if (n == 0) {
#pragma unroll
        for (int s = 0; s < 2; ++s)
#pragma unroll
            for (int j = 0; j < 4; ++j) {
                int rl = w * 32 + s * 16 + q * 4 + j;
                float xn = sqrtf(xsq_s[rl]);
                float margin = fmaf(4.0e-5f, xn, 2.0e-4f);
                bool fb = (m2[s][j] - m1[s][j]) <= 2.0f * margin;
                idx_s[rl] = ix[s][j] | (fb ? (1 << 30) : 0);
            }
    }
    __syncthreads();

    // ---- outputs ----
    if (t < 128) {
        int e = idx_s[t];
        int row = blockIdx.x * 128 + t;
        out_idx[row] = (float)(e & 0x3FFFFFFF);
        if (e >> 30) {
            int pos = atomicAdd(cnt, 1);
            if (pos < WL_CAP) wl[pos] = row;
        }
    }
    {
        int row = blockIdx.x * 128 + (t >> 1);
        int seg = (t & 1) * 32;
        int id = idx_s[t >> 1] & 0x3FFFFFFF;
        const float4* xs = (const float4*)(x_all + (size_t)row * D_DIM + seg);
        const float4* cs = (const float4*)(cb + (size_t)id * D_DIM + seg);
        float4* rs = (float4*)(out_res + (size_t)row * D_DIM + seg);
        float4* es = (float4*)(out_emb + (size_t)row * D_DIM + seg);
#pragma unroll
        for (int j = 0; j < 8; ++j) {
            float4 xv = xs[j], cv = cs[j];
            float4 rv;
            rv.x = xv.x - cv.x; rv.y = xv.y - cv.y;
            rv.z = xv.z - cv.z; rv.w = xv.w - cv.w;
            rs[j] = rv;
            es[j] = cv;
        }
    }
}

// ---------------------------------------------------------------------------
// Fallback: exact fp32 rescan of worklist rows. Arithmetic is bit-identical
// to the round-1 kernel (which matched np with absmax 0.0 on every row).
// ---------------------------------------------------------------------------
__global__ __launch_bounds__(256) void fallback_kernel(
        const float* __restrict__ x_all, const float* __restrict__ cb,
        const float* __restrict__ c_sq, const int* __restrict__ wl,
        const int* __restrict__ cnt,
        float* __restrict__ out_idx, float* __restrict__ out_res,
        float* __restrict__ out_emb) {
    int count = *cnt;
    if (count > WL_CAP) count = WL_CAP;
    for (int i = blockIdx.x * 256 + threadIdx.x; i < count; i += 64 * 256) {
        int r = wl[i];
        float x[D_DIM];
        const float4* xr = (const float4*)(x_all + (size_t)r * D_DIM);
#pragma unroll
        for (int j = 0; j < D_DIM / 4; ++j) {
            float4 v = xr[j];
            x[4 * j + 0] = v.x; x[4 * j + 1] = v.y;
            x[4 * j + 2] = v.z; x[4 * j + 3] = v.w;
        }
        float x_sq = 0.0f;
#pragma unroll
        for (int d = 0; d < D_DIM; ++d) x_sq = fmaf(x[d], x[d], x_sq);

        float best = INFINITY;
        int bidx = 0;
#pragma unroll 2
        for (int k = 0; k < K_CODES; k += 2) {
            const float* c0 = cb + (size_t)k * D_DIM;
            const float* c1 = c0 + D_DIM;
            float a00 = 0.f, a01 = 0.f, a02 = 0.f, a03 = 0.f;
            float a10 = 0.f, a11 = 0.f, a12 = 0.f, a13 = 0.f;
#pragma unroll
            for (int d = 0; d < 16; ++d) {
                a00 = fmaf(x[d],      c0[d],      a00);
                a10 = fmaf(x[d],      c1[d],      a10);
                a01 = fmaf(x[d + 16], c0[d + 16], a01);
                a11 = fmaf(x[d + 16], c1[d + 16], a11);
                a02 = fmaf(x[d + 32], c0[d + 32], a02);
                a12 = fmaf(x[d + 32], c1[d + 32], a12);
                a03 = fmaf(x[d + 48], c0[d + 48], a03);
                a13 = fmaf(x[d + 48], c1[d + 48], a13);
            }
            float dot0 = (a00 + a01) + (a02 + a03);
            float dot1 = (a10 + a11) + (a12 + a13);
            float d0 = (x_sq - 2.0f * dot0) + c_sq[k];
            float d1 = (x_sq - 2.0f * dot1) + c_sq[k + 1];
            if (d0 < best) { best = d0; bidx = k; }
            if (d1 < best) { best = d1; bidx = k + 1; }
        }
        const float4* cbest = (const float4*)(cb + (size_t)bidx * D_DIM);
        float4* res = (float4*)(out_res + (size_t)r * D_DIM);
        float4* emb = (float4*)(out_emb + (size_t)r * D_DIM);
#pragma unroll
        for (int j = 0; j < D_DIM / 4; ++j) {
            float4 c = cbest[j];
            float4 v;
            v.x = x[4 * j + 0] - c.x; v.y = x[4 * j + 1] - c.y;
            v.z = x[4 * j + 2] - c.z; v.w = x[4 * j + 3] - c.w;
            res[j] = v;
            emb[j] = c;
        }
        out_idx[r] = (float)bidx;
    }
}

extern "C" void kernel_launch(void* const* d_in, const int* in_sizes, int n_in,
                              void* d_out, int out_size, void* d_ws, size_t ws_size,
                              hipStream_t stream) {
    const float* x  = (const float*)d_in[0];
    const float* cb = (const float*)d_in[1];

    char* base = (char*)d_ws;
    ushortT* cbh = (ushortT*)base;                         // 128 KB
    ushortT* cbl = (ushortT*)(base + 131072);              // 128 KB
    float*   csq = (float*)(base + 262144);                // 4 KB
    int*     cnt = (int*)(base + 266240);
    int*     wl  = (int*)(base + 266256);                  // 256 KB

    float* out   = (float*)d_out;
    float* o_idx = out;
    float* o_res = out + (size_t)N_ROWS;
    float* o_emb = o_res + (size_t)N_ROWS * D_DIM;

    prep_kernel<<<4, 256, 0, stream>>>(cb, cbh, cbl, csq, cnt);
    coarse_kernel<<<N_ROWS / 128, 256, 0, stream>>>(x, cb, cbh, cbl, csq,
                                                    o_idx, o_res, o_emb, cnt, wl);
    fallback_kernel<<<64, 256, 0, stream>>>(x, cb, csq, wl, cnt,
                                            o_idx, o_res, o_emb);
}

// Round 3
// 484.873 us; speedup vs baseline: 3.7554x; 2.0017x over previous
//
#include <hip/hip_runtime.h>
#include <math.h>

#define N_ROWS 262144
#define K_CODES 1024
#define D_DIM 64
#define WL_CAP 65536

typedef __attribute__((ext_vector_type(8))) short short8;
typedef __attribute__((ext_vector_type(4))) float f32x4;
typedef unsigned short ushortT;
typedef unsigned int uintT;

// bf16 round-to-nearest-even of a finite fp32, returned as raw bf16 bits.
__device__ inline uintT bf16_rne_bits(float v) {
    uintT u = __float_as_uint(v);
    return (u + 0x7FFFu + ((u >> 16) & 1u)) >> 16;
}

// ---------------------------------------------------------------------------
// Prep: c_sq (EXACT same accumulation order as the round-1 kernel that
// matched np with absmax 0.0), codebook bf16 hi/lo split, counter zero.
// ---------------------------------------------------------------------------
__global__ __launch_bounds__(256) void prep_kernel(const float* __restrict__ cb,
                                                   ushortT* __restrict__ cbh,
                                                   ushortT* __restrict__ cbl,
                                                   float* __restrict__ c_sq,
                                                   int* __restrict__ cnt) {
    if (blockIdx.x == 0 && threadIdx.x == 0) *cnt = 0;
    int k = blockIdx.x * 256 + threadIdx.x;
    if (k >= K_CODES) return;
    const float4* row = (const float4*)(cb + (size_t)k * D_DIM);
    float s = 0.0f;
#pragma unroll
    for (int j = 0; j < D_DIM / 4; ++j) {
        float4 v = row[j];
        s = fmaf(v.x, v.x, s);
        s = fmaf(v.y, v.y, s);
        s = fmaf(v.z, v.z, s);
        s = fmaf(v.w, v.w, s);
        float e[4] = {v.x, v.y, v.z, v.w};
#pragma unroll
        for (int q = 0; q < 4; ++q) {
            int d = 4 * j + q;
            uintT hb = bf16_rne_bits(e[q]);
            float hif = __uint_as_float(hb << 16);
            uintT lb = bf16_rne_bits(e[q] - hif);
            cbh[(size_t)k * D_DIM + d] = (ushortT)hb;
            cbl[(size_t)k * D_DIM + d] = (ushortT)lb;
        }
    }
    c_sq[k] = s;
}

// ---------------------------------------------------------------------------
// Coarse: 3-pass split-bf16 MFMA distances, per-row min1/min2/argmin,
// hard-bound gap test, direct output write; uncertain rows -> worklist.
// Block = 256 thr = 4 waves; wave handles 32 rows (2 rowsets of 16) x all K.
// ---------------------------------------------------------------------------
__global__ __launch_bounds__(256, 3) void coarse_kernel(
        const float* __restrict__ x_all, const float* __restrict__ cb,
        const ushortT* __restrict__ cbh, const ushortT* __restrict__ cbl,
        const float* __restrict__ c_sq_g,
        float* __restrict__ out_idx, float* __restrict__ out_res,
        float* __restrict__ out_emb, int* __restrict__ cnt,
        int* __restrict__ wl) {
    __shared__ uint4 stage4[2048];          // 32 KB: one round = 8 tiles of 16 codes, hi+lo
    __shared__ float csq_s[128];
    __shared__ float xsq_s[128];
    __shared__ int   idx_s[128];
    ushortT* stage = (ushortT*)stage4;

    const int t  = threadIdx.x;
    const int w  = t >> 6;          // wave 0..3
    const int L  = t & 63;          // lane
    const int q  = L >> 4;          // quad 0..3
    const int n  = L & 15;          // class / col
    const int rowbase = blockIdx.x * 128 + w * 32;

    // ---- load + convert A fragments (x rows), compute x_sq ----
    short8 ah[2][2], al[2][2];
#pragma unroll
    for (int s = 0; s < 2; ++s) {
        float part = 0.0f;
#pragma unroll
        for (int kt = 0; kt < 2; ++kt) {
            const float4* p = (const float4*)(x_all +
                (size_t)(rowbase + s * 16 + n) * D_DIM + kt * 32 + q * 8);
            float4 v0 = p[0], v1 = p[1];
            float e[8] = {v0.x, v0.y, v0.z, v0.w, v1.x, v1.y, v1.z, v1.w};
#pragma unroll
            for (int j = 0; j < 8; ++j) {
                part = fmaf(e[j], e[j], part);
                uintT hb = bf16_rne_bits(e[j]);
                float hif = __uint_as_float(hb << 16);
                uintT lb = bf16_rne_bits(e[j] - hif);
                ah[s][kt][j] = (short)hb;
                al[s][kt][j] = (short)lb;
            }
        }
        // reduce over quads (lanes n, n+16, n+32, n+48)
        part += __shfl_xor(part, 16);
        part += __shfl_xor(part, 32);
        if (q == 0) xsq_s[w * 32 + s * 16 + n] = part;
    }

    // ---- tracking state: per (rowset s, reg j) = per (row, class) ----
    float m1[2][4], m2[2][4];
    int   ix[2][4];
#pragma unroll
    for (int s = 0; s < 2; ++s)
#pragma unroll
        for (int j = 0; j < 4; ++j) { m1[s][j] = 3.4e38f; m2[s][j] = 3.4e38f; ix[s][j] = 0; }

    // ---- prologue: prefetch round 0 staging into registers ----
    uint4 pre[8];
    float cpre = 0.0f;
#pragma unroll
    for (int it = 0; it < 8; ++it) {
        int chunk = it * 256 + t;
        int tile = chunk >> 8, c = chunk & 255;
        int hilo = (c >> 7) & 1, cc = c & 127;
        int kt = cc >> 6, LL = cc & 63;
        const ushortT* src = hilo ? cbl : cbh;
        size_t elem = (size_t)(tile * 16 + (LL & 15)) * D_DIM + kt * 32 + (LL >> 4) * 8;
        pre[it] = *(const uint4*)(src + elem);
    }
    if (t < 128) cpre = c_sq_g[t];

    for (int r = 0; r < 8; ++r) {
        __syncthreads();                       // previous round's compute done
#pragma unroll
        for (int it = 0; it < 8; ++it)
            *(uint4*)(stage + (it * 256 + t) * 8) = pre[it];
        if (t < 128) csq_s[t] = cpre;
        __syncthreads();                       // staging visible

        if (r < 7) {                           // prefetch next round (overlaps compute)
            int rn = r + 1;
#pragma unroll
            for (int it = 0; it < 8; ++it) {
                int chunk = it * 256 + t;
                int tile = chunk >> 8, c = chunk & 255;
                int hilo = (c >> 7) & 1, cc = c & 127;
                int kt = cc >> 6, LL = cc & 63;
                const ushortT* src = hilo ? cbl : cbh;
                size_t elem = (size_t)(rn * 128 + tile * 16 + (LL & 15)) * D_DIM +
                              kt * 32 + (LL >> 4) * 8;
                pre[it] = *(const uint4*)(src + elem);
            }
            if (t < 128) cpre = c_sq_g[rn * 128 + t];
        }

        // ---- compute 8 tiles from LDS ----
#pragma unroll
        for (int tl = 0; tl < 8; ++tl) {
            const int tb = tl * 2048;          // ushort offset of tile
            short8 bh0 = *(const short8*)(stage + tb +        0 * 512 + L * 8);
            short8 bh1 = *(const short8*)(stage + tb +        1 * 512 + L * 8);
            short8 bl0 = *(const short8*)(stage + tb + 1024 + 0 * 512 + L * 8);
            short8 bl1 = *(const short8*)(stage + tb + 1024 + 1 * 512 + L * 8);

            f32x4 acc0 = {0.f, 0.f, 0.f, 0.f};
            f32x4 acc1 = {0.f, 0.f, 0.f, 0.f};
            acc0 = __builtin_amdgcn_mfma_f32_16x16x32_bf16(ah[0][0], bh0, acc0, 0, 0, 0);
            acc1 = __builtin_amdgcn_mfma_f32_16x16x32_bf16(ah[1][0], bh0, acc1, 0, 0, 0);
            acc0 = __builtin_amdgcn_mfma_f32_16x16x32_bf16(ah[0][1], bh1, acc0, 0, 0, 0);
            acc1 = __builtin_amdgcn_mfma_f32_16x16x32_bf16(ah[1][1], bh1, acc1, 0, 0, 0);
            acc0 = __builtin_amdgcn_mfma_f32_16x16x32_bf16(ah[0][0], bl0, acc0, 0, 0, 0);
            acc1 = __builtin_amdgcn_mfma_f32_16x16x32_bf16(ah[1][0], bl0, acc1, 0, 0, 0);
            acc0 = __builtin_amdgcn_mfma_f32_16x16x32_bf16(ah[0][1], bl1, acc0, 0, 0, 0);
            acc1 = __builtin_amdgcn_mfma_f32_16x16x32_bf16(ah[1][1], bl1, acc1, 0, 0, 0);
            acc0 = __builtin_amdgcn_mfma_f32_16x16x32_bf16(al[0][0], bh0, acc0, 0, 0, 0);
            acc1 = __builtin_amdgcn_mfma_f32_16x16x32_bf16(al[1][0], bh0, acc1, 0, 0, 0);
            acc0 = __builtin_amdgcn_mfma_f32_16x16x32_bf16(al[0][1], bh1, acc0, 0, 0, 0);
            acc1 = __builtin_amdgcn_mfma_f32_16x16x32_bf16(al[1][1], bh1, acc1, 0, 0, 0);

            float cv = csq_s[tl * 16 + n];
            int kc = r * 128 + tl * 16 + n;
#pragma unroll
            for (int j = 0; j < 4; ++j) {
                float d0 = fmaf(-2.0f, acc0[j], cv);
                bool lt0 = d0 < m1[0][j];
                m2[0][j] = lt0 ? m1[0][j] : fminf(m2[0][j], d0);
                m1[0][j] = lt0 ? d0 : m1[0][j];
                ix[0][j] = lt0 ? kc : ix[0][j];
                float d1 = fmaf(-2.0f, acc1[j], cv);
                bool lt1 = d1 < m1[1][j];
                m2[1][j] = lt1 ? m1[1][j] : fminf(m2[1][j], d1);
                m1[1][j] = lt1 ? d1 : m1[1][j];
                ix[1][j] = lt1 ? kc : ix[1][j];
            }
        }
    }

    // ---- butterfly reduce across the 16 classes (lane bits 0..3) ----
#pragma unroll
    for (int s = 0; s < 2; ++s)
#pragma unroll
        for (int j = 0; j < 4; ++j) {
            float a1 = m1[s][j], a2 = m2[s][j];
            int ai = ix[s][j];
#pragma unroll
            for (int msk = 1; msk < 16; msk <<= 1) {
                float o1 = __shfl_xor(a1, msk);
                float o2 = __shfl_xor(a2, msk);
                int oi = __shfl_xor(ai, msk);
                float nm2 = fminf(fmaxf(a1, o1), fminf(a2, o2));
                bool take = (o1 < a1) || (o1 == a1 && oi < ai);
                a1 = take ? o1 : a1;
                ai = take ? oi : ai;
                a2 = nm2;
            }
            m1[s][j] = a1; m2[s][j] = a2; ix[s][j] = ai;
        }

    // ---- gap test + record per-row result (class-0 lanes) ----
    if (n == 0) {
#pragma unroll
        for (int s = 0; s < 2; ++s)
#pragma unroll
            for (int j = 0; j < 4; ++j) {
                int rl = w * 32 + s * 16 + q * 4 + j;
                float xn = sqrtf(xsq_s[rl]);
                float margin = fmaf(4.0e-5f, xn, 2.0e-4f);
                bool fb = (m2[s][j] - m1[s][j]) <= 2.0f * margin;
                idx_s[rl] = ix[s][j] | (fb ? (1 << 30) : 0);
            }
    }
    __syncthreads();

    // ---- outputs ----
    if (t < 128) {
        int e = idx_s[t];
        int row = blockIdx.x * 128 + t;
        out_idx[row] = (float)(e & 0x3FFFFFFF);
        if (e >> 30) {
            int pos = atomicAdd(cnt, 1);
            if (pos < WL_CAP) wl[pos] = row;
        }
    }
    {
        int row = blockIdx.x * 128 + (t >> 1);
        int seg = (t & 1) * 32;
        int id = idx_s[t >> 1] & 0x3FFFFFFF;
        const float4* xs = (const float4*)(x_all + (size_t)row * D_DIM + seg);
        const float4* cs = (const float4*)(cb + (size_t)id * D_DIM + seg);
        float4* rs = (float4*)(out_res + (size_t)row * D_DIM + seg);
        float4* es = (float4*)(out_emb + (size_t)row * D_DIM + seg);
#pragma unroll
        for (int j = 0; j < 8; ++j) {
            float4 xv = xs[j], cv = cs[j];
            float4 rv;
            rv.x = xv.x - cv.x; rv.y = xv.y - cv.y;
            rv.z = xv.z - cv.z; rv.w = xv.w - cv.w;
            rs[j] = rv;
            es[j] = cv;
        }
    }
}

// ---------------------------------------------------------------------------
// Fallback: exact fp32 rescan of worklist rows. WAVE-PER-ROW: lane L handles
// codes {L, L+64, ..., L+960} with per-lane float4 vector loads (16
// independent loads per code -> pipelined latency, vs round-2's serial
// scalar-load chain that ran at 0.3% VALUBusy for 900us). Per-code distance
// arithmetic is bit-identical to the round-1 exact kernel (absmax 0.0 vs np).
// Cross-lane argmin butterfly keeps first-occurrence tie-break semantics.
// ---------------------------------------------------------------------------
__global__ __launch_bounds__(256) void fallback_kernel(
        const float* __restrict__ x_all, const float* __restrict__ cb,
        const float* __restrict__ c_sq, const int* __restrict__ wl,
        const int* __restrict__ cnt,
        float* __restrict__ out_idx, float* __restrict__ out_res,
        float* __restrict__ out_emb) {
    int count = *cnt;
    if (count > WL_CAP) count = WL_CAP;
    const int L = threadIdx.x & 63;
    const int waveId = blockIdx.x * 4 + (threadIdx.x >> 6);
    const int nWaves = gridDim.x * 4;

    for (int i = waveId; i < count; i += nWaves) {
        int r = wl[i];

        // every lane loads the full row (broadcast, L1-hot after first lane)
        float x[D_DIM];
        const float4* xr = (const float4*)(x_all + (size_t)r * D_DIM);
#pragma unroll
        for (int j = 0; j < D_DIM / 4; ++j) {
            float4 v = xr[j];
            x[4 * j + 0] = v.x; x[4 * j + 1] = v.y;
            x[4 * j + 2] = v.z; x[4 * j + 3] = v.w;
        }
        float x_sq = 0.0f;
#pragma unroll
        for (int d = 0; d < D_DIM; ++d) x_sq = fmaf(x[d], x[d], x_sq);

        float best = INFINITY;
        int bidx = 0x7FFFFFFF;
        // lane L scans codes L, L+64, ... ascending -> strict '<' keeps
        // first-occurrence within the lane's subset.
        for (int kk = 0; kk < 16; ++kk) {
            int k = kk * 64 + L;
            const float* c0 = cb + (size_t)k * D_DIM;
            float a00 = 0.f, a01 = 0.f, a02 = 0.f, a03 = 0.f;
#pragma unroll
            for (int j = 0; j < 4; ++j) {
                float4 v0 = *(const float4*)(c0 + 16 * j + 0);
                float4 v1 = *(const float4*)(c0 + 16 * j + 4);
                float4 v2 = *(const float4*)(c0 + 16 * j + 8);
                float4 v3 = *(const float4*)(c0 + 16 * j + 12);
                float* a = (j == 0) ? &a00 : (j == 1) ? &a01 : (j == 2) ? &a02 : &a03;
                float acc = *a;
                acc = fmaf(x[16 * j + 0],  v0.x, acc);
                acc = fmaf(x[16 * j + 1],  v0.y, acc);
                acc = fmaf(x[16 * j + 2],  v0.z, acc);
                acc = fmaf(x[16 * j + 3],  v0.w, acc);
                acc = fmaf(x[16 * j + 4],  v1.x, acc);
                acc = fmaf(x[16 * j + 5],  v1.y, acc);
                acc = fmaf(x[16 * j + 6],  v1.z, acc);
                acc = fmaf(x[16 * j + 7],  v1.w, acc);
                acc = fmaf(x[16 * j + 8],  v2.x, acc);
                acc = fmaf(x[16 * j + 9],  v2.y, acc);
                acc = fmaf(x[16 * j + 10], v2.z, acc);
                acc = fmaf(x[16 * j + 11], v2.w, acc);
                acc = fmaf(x[16 * j + 12], v3.x, acc);
                acc = fmaf(x[16 * j + 13], v3.y, acc);
                acc = fmaf(x[16 * j + 14], v3.z, acc);
                acc = fmaf(x[16 * j + 15], v3.w, acc);
                *a = acc;
            }
            float dot = (a00 + a01) + (a02 + a03);
            float d = (x_sq - 2.0f * dot) + c_sq[k];
            if (d < best) { best = d; bidx = k; }
        }

        // cross-lane argmin, smaller-index tie-break => global first-occurrence
#pragma unroll
        for (int msk = 1; msk < 64; msk <<= 1) {
            float ob = __shfl_xor(best, msk);
            int oi = __shfl_xor(bidx, msk);
            bool take = (ob < best) || (ob == best && oi < bidx);
            best = take ? ob : best;
            bidx = take ? oi : bidx;
        }

        // epilogue: lanes 0..15 write 4 floats each
        if (L < 16) {
            const float4* cbest = (const float4*)(cb + (size_t)bidx * D_DIM);
            float4 c = cbest[L];
            float4 v;
            v.x = x[4 * L + 0] - c.x; v.y = x[4 * L + 1] - c.y;
            v.z = x[4 * L + 2] - c.z; v.w = x[4 * L + 3] - c.w;
            ((float4*)(out_res + (size_t)r * D_DIM))[L] = v;
            ((float4*)(out_emb + (size_t)r * D_DIM))[L] = c;
            if (L == 0) out_idx[r] = (float)bidx;
        }
    }
}

extern "C" void kernel_launch(void* const* d_in, const int* in_sizes, int n_in,
                              void* d_out, int out_size, void* d_ws, size_t ws_size,
                              hipStream_t stream) {
    const float* x  = (const float*)d_in[0];
    const float* cb = (const float*)d_in[1];

    char* base = (char*)d_ws;
    ushortT* cbh = (ushortT*)base;                         // 128 KB
    ushortT* cbl = (ushortT*)(base + 131072);              // 128 KB
    float*   csq = (float*)(base + 262144);                // 4 KB
    int*     cnt = (int*)(base + 266240);
    int*     wl  = (int*)(base + 266256);                  // 256 KB

    float* out   = (float*)d_out;
    float* o_idx = out;
    float* o_res = out + (size_t)N_ROWS;
    float* o_emb = o_res + (size_t)N_ROWS * D_DIM;

    prep_kernel<<<4, 256, 0, stream>>>(cb, cbh, cbl, csq, cnt);
    coarse_kernel<<<N_ROWS / 128, 256, 0, stream>>>(x, cb, cbh, cbl, csq,
                                                    o_idx, o_res, o_emb, cnt, wl);
    fallback_kernel<<<1024, 256, 0, stream>>>(x, cb, csq, wl, cnt,
                                              o_idx, o_res, o_emb);
}